// Round 10
// baseline (295.378 us; speedup 1.0000x reference)
//
#include <hip/hip_runtime.h>

#define DIM 64
#define SCAN_B 256
#define BKT_SHIFT 7          // 128 nodes per bucket
#define BKT_G 128
#define NBLK 256             // blocks in hist/place (MUST == SCAN_B: bucket==chunk)
#define HIST_B 1024          // threads for hist/place
#define NREP 4               // LDS histogram replicas (contention /4)
#define RCAP 20              // records held in regs per pass2 thread (m<=5120)
// NOTE: src packed in 17 bits -> requires N <= 131072 (N=100000 here)

// ---------------- bf16x2 helpers (pack with round-to-nearest-even) ---------
__device__ inline float blo(unsigned p) { return __uint_as_float(p << 16); }
__device__ inline float bhi(unsigned p) { return __uint_as_float(p & 0xffff0000u); }
__device__ inline unsigned bpack(float x, float y) {
    unsigned ux = __float_as_uint(x);
    unsigned uy = __float_as_uint(y);
    ux += 0x7fffu + ((ux >> 16) & 1u);
    uy += 0x7fffu + ((uy >> 16) & 1u);
    return (ux >> 16) | (uy & 0xffff0000u);
}

// ---------------------------------------------------------------------------
// Pass A: per-(block,bucket) LDS histogram, 4 replicas, int4 edge loads.
// Edge->block mapping MUST match place_kernel exactly (same grid-stride).
// ---------------------------------------------------------------------------
__global__ __launch_bounds__(HIST_B)
void hist_kernel(const int* __restrict__ adj, int E,
                 int* __restrict__ hist, int NB) {
    extern __shared__ int lh[];            // NREP * NB
    for (int g = threadIdx.x; g < NREP * NB; g += blockDim.x) lh[g] = 0;
    __syncthreads();
    const int rep = (threadIdx.x & (NREP - 1)) * NB;
    const int n4 = E >> 2;
    const int4* srcs = (const int4*)adj;
    const int4* dsts = (const int4*)(adj + E);
    for (int i = blockIdx.x * blockDim.x + threadIdx.x; i < n4;
         i += NBLK * blockDim.x) {
        int4 a = srcs[i];
        int4 b = dsts[i];
        atomicAdd(&lh[rep + (a.x >> BKT_SHIFT)], 1);
        atomicAdd(&lh[rep + (a.y >> BKT_SHIFT)], 1);
        atomicAdd(&lh[rep + (a.z >> BKT_SHIFT)], 1);
        atomicAdd(&lh[rep + (a.w >> BKT_SHIFT)], 1);
        atomicAdd(&lh[rep + (b.x >> BKT_SHIFT)], 1);
        atomicAdd(&lh[rep + (b.y >> BKT_SHIFT)], 1);
        atomicAdd(&lh[rep + (b.z >> BKT_SHIFT)], 1);
        atomicAdd(&lh[rep + (b.w >> BKT_SHIFT)], 1);
    }
    if (blockIdx.x == 0) {                 // scalar tail (E%4), block 0 only
        for (int e = (n4 << 2) + threadIdx.x; e < E; e += blockDim.x) {
            atomicAdd(&lh[rep + (adj[e] >> BKT_SHIFT)], 1);
            atomicAdd(&lh[rep + (adj[E + e] >> BKT_SHIFT)], 1);
        }
    }
    __syncthreads();
    for (int g = threadIdx.x; g < NB; g += blockDim.x)
        hist[g * NBLK + blockIdx.x] =
            lh[g] + lh[NB + g] + lh[2 * NB + g] + lh[3 * NB + g];
}

// --------------------------- prefix scan (2 stages) ------------------------
// NBLK == SCAN_B => bucket base offset == bsums[g]; scan_add fused into
// consumers.
__global__ void scan_block_kernel(const int* __restrict__ src, int n,
                                  int* __restrict__ dst,
                                  int* __restrict__ blocksums) {
    __shared__ int tmp[SCAN_B];
    int i = blockIdx.x * SCAN_B + threadIdx.x;
    int v = (i < n) ? src[i] : 0;
    tmp[threadIdx.x] = v;
    __syncthreads();
    for (int off = 1; off < SCAN_B; off <<= 1) {
        int t = (threadIdx.x >= off) ? tmp[threadIdx.x - off] : 0;
        __syncthreads();
        tmp[threadIdx.x] += t;
        __syncthreads();
    }
    if (i < n) dst[i] = tmp[threadIdx.x] - v;           // chunk-exclusive
    if (threadIdx.x == SCAN_B - 1) blocksums[blockIdx.x] = tmp[SCAN_B - 1];
}

__global__ void scan_sums_kernel(int* __restrict__ blocksums, int nb) {
    __shared__ int tmp[1024];
    int v = (threadIdx.x < nb) ? blocksums[threadIdx.x] : 0;
    tmp[threadIdx.x] = v;
    __syncthreads();
    for (int off = 1; off < 1024; off <<= 1) {
        int t = (threadIdx.x >= off) ? tmp[threadIdx.x - off] : 0;
        __syncthreads();
        tmp[threadIdx.x] += t;
        __syncthreads();
    }
    if (threadIdx.x < nb) blocksums[threadIdx.x] = tmp[threadIdx.x] - v;  // exclusive
}

// ---------------------------------------------------------------------------
// Pass C: placement, int4 edge loads, scan fix-up fused (cur = hist_s+bsums).
// record = (dstLocal << 17) | src
// ---------------------------------------------------------------------------
__global__ __launch_bounds__(HIST_B)
void place_kernel(const int* __restrict__ adj, int E,
                  const int* __restrict__ hist_s,
                  const int* __restrict__ bsums,
                  unsigned* __restrict__ pairs, int NB) {
    extern __shared__ int cur[];
    for (int g = threadIdx.x; g < NB; g += blockDim.x)
        cur[g] = hist_s[g * NBLK + blockIdx.x] + bsums[g];
    __syncthreads();
    const int n4 = E >> 2;
    const int4* srcs = (const int4*)adj;
    const int4* dsts = (const int4*)(adj + E);
    for (int i = blockIdx.x * blockDim.x + threadIdx.x; i < n4;
         i += NBLK * blockDim.x) {
        int4 a = srcs[i];
        int4 b = dsts[i];
        int p;
        p = atomicAdd(&cur[b.x >> BKT_SHIFT], 1);
        pairs[p] = ((unsigned)(b.x & (BKT_G - 1)) << 17) | (unsigned)a.x;
        p = atomicAdd(&cur[a.x >> BKT_SHIFT], 1);
        pairs[p] = ((unsigned)(a.x & (BKT_G - 1)) << 17) | (unsigned)b.x;
        p = atomicAdd(&cur[b.y >> BKT_SHIFT], 1);
        pairs[p] = ((unsigned)(b.y & (BKT_G - 1)) << 17) | (unsigned)a.y;
        p = atomicAdd(&cur[a.y >> BKT_SHIFT], 1);
        pairs[p] = ((unsigned)(a.y & (BKT_G - 1)) << 17) | (unsigned)b.y;
        p = atomicAdd(&cur[b.z >> BKT_SHIFT], 1);
        pairs[p] = ((unsigned)(b.z & (BKT_G - 1)) << 17) | (unsigned)a.z;
        p = atomicAdd(&cur[a.z >> BKT_SHIFT], 1);
        pairs[p] = ((unsigned)(a.z & (BKT_G - 1)) << 17) | (unsigned)b.z;
        p = atomicAdd(&cur[b.w >> BKT_SHIFT], 1);
        pairs[p] = ((unsigned)(b.w & (BKT_G - 1)) << 17) | (unsigned)a.w;
        p = atomicAdd(&cur[a.w >> BKT_SHIFT], 1);
        pairs[p] = ((unsigned)(a.w & (BKT_G - 1)) << 17) | (unsigned)b.w;
    }
    if (blockIdx.x == 0) {                 // scalar tail, same rule as hist
        for (int e = (n4 << 2) + threadIdx.x; e < E; e += blockDim.x) {
            int a = adj[e];
            int b = adj[E + e];
            int p1 = atomicAdd(&cur[b >> BKT_SHIFT], 1);
            pairs[p1] = ((unsigned)(b & (BKT_G - 1)) << 17) | (unsigned)a;
            int p2 = atomicAdd(&cur[a >> BKT_SHIFT], 1);
            pairs[p2] = ((unsigned)(a & (BKT_G - 1)) << 17) | (unsigned)b;
        }
    }
}

// ---------------------------------------------------------------------------
// Pass D (one block of 256 per bucket): single pairs read, records in regs;
// emits deg/dinv/row_ptr coalesced + csr scatter + fused xs0 = bf16(dinv*x0).
// ---------------------------------------------------------------------------
__global__ __launch_bounds__(256)
void pass2_build_kernel(const unsigned* __restrict__ pairs,
                        const int* __restrict__ bsums,
                        const float4* __restrict__ x,
                        int* __restrict__ csr_src,
                        int* __restrict__ row_ptr,
                        int* __restrict__ deg,
                        float* __restrict__ dinv,
                        uint4* __restrict__ xs0,
                        int N, int NB, int total_adj) {
    __shared__ int cnt[BKT_G];
    __shared__ int pre[BKT_G];
    __shared__ int cur[BKT_G];
    __shared__ float dv[BKT_G];
    int g = blockIdx.x;
    int base = g << BKT_SHIFT;
    int off  = bsums[g];
    int offn = (g + 1 < NB) ? bsums[g + 1] : total_adj;
    if (threadIdx.x < BKT_G) cnt[threadIdx.x] = 0;
    __syncthreads();
    unsigned rec[RCAP];
    int ibase = off + threadIdx.x;
#pragma unroll
    for (int k = 0; k < RCAP; ++k) {
        int i = ibase + k * 256;
        unsigned p = 0;
        if (i < offn) {
            p = pairs[i];
            atomicAdd(&cnt[p >> 17], 1);
        }
        rec[k] = p;
    }
    for (int i = ibase + RCAP * 256; i < offn; i += 256)   // overflow fallback
        atomicAdd(&cnt[pairs[i] >> 17], 1);
    __syncthreads();
    if (threadIdx.x < BKT_G) pre[threadIdx.x] = cnt[threadIdx.x];
    __syncthreads();
    for (int o = 1; o < BKT_G; o <<= 1) {
        int t = 0;
        if (threadIdx.x < BKT_G && threadIdx.x >= o) t = pre[threadIdx.x - o];
        __syncthreads();
        if (threadIdx.x < BKT_G) pre[threadIdx.x] += t;
        __syncthreads();
    }
    if (threadIdx.x < BKT_G) {
        int v = base + threadIdx.x;
        if (v < N) {
            int c = cnt[threadIdx.x];
            int start = off + pre[threadIdx.x] - c;   // exclusive
            float di = (c > 0) ? rsqrtf((float)c) : 0.0f;
            row_ptr[v] = start;
            deg[v] = c;
            dinv[v] = di;
            dv[threadIdx.x] = di;
            cur[threadIdx.x] = start;
        }
    }
    if (g == NB - 1 && threadIdx.x == 0) row_ptr[N] = total_adj;
    __syncthreads();
#pragma unroll
    for (int k = 0; k < RCAP; ++k) {
        int i = ibase + k * 256;
        if (i < offn) {
            unsigned p = rec[k];
            int pos = atomicAdd(&cur[p >> 17], 1);
            csr_src[pos] = (int)(p & 0x1ffffu);
        }
    }
    for (int i = ibase + RCAP * 256; i < offn; i += 256) { // overflow fallback
        unsigned p = pairs[i];
        int pos = atomicAdd(&cur[p >> 17], 1);
        csr_src[pos] = (int)(p & 0x1ffffu);
    }
    for (int w = threadIdx.x; w < BKT_G * 8; w += blockDim.x) {
        int vl = w >> 3, sub = w & 7;
        int v = base + vl;
        if (v < N) {
            float di = dv[vl];
            float4 xa = x[(size_t)v * 16 + sub * 2];
            float4 xb = x[(size_t)v * 16 + sub * 2 + 1];
            uint4 o;
            o.x = bpack(di * xa.x, di * xa.y);
            o.y = bpack(di * xa.z, di * xa.w);
            o.z = bpack(di * xb.x, di * xb.y);
            o.w = bpack(di * xb.z, di * xb.w);
            xs0[(size_t)v * 8 + sub] = o;
        }
    }
}

// --------------------- SpMM accumulation (shared body) ---------------------
// 32 lanes per node: 16 neighbors/iter. TWO-DEEP GATHER PIPELINE (R10):
// iteration i+1's gathers (Q) are issued BEFORE iteration i's accumulate
// consumes P, so the vmcnt wait for P leaves Q + index loads in flight.
// Indices prefetched 2 iterations ahead. Loop runs full-1 times + epilogue
// so the main loop is maskless and no gather is wasted.
#define SPMM_ACCUM_BODY                                                        \
    int half = threadIdx.x & 31;                                               \
    int nb = half >> 3, sub = half & 7;                                        \
    int beg = row_ptr[v];                                                      \
    int end = row_ptr[v + 1];                                                  \
    int full = (end - beg) >> 4;                                               \
    float a0 = 0, a1 = 0, a2 = 0, a3 = 0, a4 = 0, a5 = 0, a6 = 0, a7 = 0;      \
    int j = beg;                                                               \
    if (full > 0) {                                                            \
        int b0 = j + 4 * nb;                                                   \
        int s0 = csr_src[b0],     s1 = csr_src[b0 + 1];                        \
        int s2 = csr_src[b0 + 2], s3 = csr_src[b0 + 3];                        \
        uint4 P0 = xs_in[(size_t)s0 * 8 + sub];                                \
        uint4 P1 = xs_in[(size_t)s1 * 8 + sub];                                \
        uint4 P2 = xs_in[(size_t)s2 * 8 + sub];                                \
        uint4 P3 = xs_in[(size_t)s3 * 8 + sub];                                \
        int n0 = 0, n1 = 0, n2 = 0, n3 = 0;                                    \
        if (full > 1) {                                                        \
            int b1 = b0 + 16;                                                  \
            n0 = csr_src[b1];     n1 = csr_src[b1 + 1];                        \
            n2 = csr_src[b1 + 2]; n3 = csr_src[b1 + 3];                        \
        }                                                                      \
        for (int it = 0; it < full - 1; ++it) {                                \
            uint4 Q0 = xs_in[(size_t)n0 * 8 + sub];                            \
            uint4 Q1 = xs_in[(size_t)n1 * 8 + sub];                            \
            uint4 Q2 = xs_in[(size_t)n2 * 8 + sub];                            \
            uint4 Q3 = xs_in[(size_t)n3 * 8 + sub];                            \
            int m0 = 0, m1 = 0, m2 = 0, m3 = 0;                                \
            if (it + 2 < full) {                                               \
                int b2 = j + 32 + 4 * nb;                                      \
                m0 = csr_src[b2];     m1 = csr_src[b2 + 1];                    \
                m2 = csr_src[b2 + 2]; m3 = csr_src[b2 + 3];                    \
            }                                                                  \
            a0 += (blo(P0.x) + blo(P1.x)) + (blo(P2.x) + blo(P3.x));           \
            a1 += (bhi(P0.x) + bhi(P1.x)) + (bhi(P2.x) + bhi(P3.x));           \
            a2 += (blo(P0.y) + blo(P1.y)) + (blo(P2.y) + blo(P3.y));           \
            a3 += (bhi(P0.y) + bhi(P1.y)) + (bhi(P2.y) + bhi(P3.y));           \
            a4 += (blo(P0.z) + blo(P1.z)) + (blo(P2.z) + blo(P3.z));           \
            a5 += (bhi(P0.z) + bhi(P1.z)) + (bhi(P2.z) + bhi(P3.z));           \
            a6 += (blo(P0.w) + blo(P1.w)) + (blo(P2.w) + blo(P3.w));           \
            a7 += (bhi(P0.w) + bhi(P1.w)) + (bhi(P2.w) + bhi(P3.w));           \
            P0 = Q0; P1 = Q1; P2 = Q2; P3 = Q3;                                \
            n0 = m0; n1 = m1; n2 = m2; n3 = m3;                                \
            j += 16;                                                           \
        }                                                                      \
        a0 += (blo(P0.x) + blo(P1.x)) + (blo(P2.x) + blo(P3.x));               \
        a1 += (bhi(P0.x) + bhi(P1.x)) + (bhi(P2.x) + bhi(P3.x));               \
        a2 += (blo(P0.y) + blo(P1.y)) + (blo(P2.y) + blo(P3.y));               \
        a3 += (bhi(P0.y) + bhi(P1.y)) + (bhi(P2.y) + bhi(P3.y));               \
        a4 += (blo(P0.z) + blo(P1.z)) + (blo(P2.z) + blo(P3.z));               \
        a5 += (bhi(P0.z) + bhi(P1.z)) + (bhi(P2.z) + bhi(P3.z));               \
        a6 += (blo(P0.w) + blo(P1.w)) + (blo(P2.w) + blo(P3.w));               \
        a7 += (bhi(P0.w) + bhi(P1.w)) + (bhi(P2.w) + bhi(P3.w));               \
        j += 16;                                                               \
    }                                                                          \
    for (int idx = j + nb; idx < end; idx += 4) {                              \
        int s = csr_src[idx];                                                  \
        uint4 p = xs_in[(size_t)s * 8 + sub];                                  \
        a0 += blo(p.x); a1 += bhi(p.x);                                        \
        a2 += blo(p.y); a3 += bhi(p.y);                                        \
        a4 += blo(p.z); a5 += bhi(p.z);                                        \
        a6 += blo(p.w); a7 += bhi(p.w);                                        \
    }                                                                          \
    a0 += __shfl_xor(a0, 8);  a0 += __shfl_xor(a0, 16);                        \
    a1 += __shfl_xor(a1, 8);  a1 += __shfl_xor(a1, 16);                        \
    a2 += __shfl_xor(a2, 8);  a2 += __shfl_xor(a2, 16);                        \
    a3 += __shfl_xor(a3, 8);  a3 += __shfl_xor(a3, 16);                        \
    a4 += __shfl_xor(a4, 8);  a4 += __shfl_xor(a4, 16);                        \
    a5 += __shfl_xor(a5, 8);  a5 += __shfl_xor(a5, 16);                        \
    a6 += __shfl_xor(a6, 8);  a6 += __shfl_xor(a6, 16);                        \
    a7 += __shfl_xor(a7, 8);  a7 += __shfl_xor(a7, 16);

// Layers 1,2: xs_out = bf16(dinv^2 * acc)
__global__ void spmm_bf16_kernel(const int* __restrict__ row_ptr,
                                 const int* __restrict__ csr_src,
                                 const float* __restrict__ dinv,
                                 const uint4* __restrict__ xs_in,
                                 uint4* __restrict__ xs_out, int N) {
    int t = blockIdx.x * blockDim.x + threadIdx.x;
    int v = t >> 5;
    if (v >= N) return;
    SPMM_ACCUM_BODY
    if (nb == 0) {
        float di = dinv[v];
        float d2 = di * di;
        uint4 o;
        o.x = bpack(d2 * a0, d2 * a1);
        o.y = bpack(d2 * a2, d2 * a3);
        o.z = bpack(d2 * a4, d2 * a5);
        o.w = bpack(d2 * a6, d2 * a7);
        xs_out[(size_t)v * 8 + sub] = o;
    }
}

// Layer 3 fused with final: out = 0.25*(x0 + rs*(xs1+xs2) + dinv*acc)
__global__ void spmm_last_kernel(const int* __restrict__ row_ptr,
                                 const int* __restrict__ csr_src,
                                 const float* __restrict__ dinv,
                                 const int* __restrict__ deg,
                                 const uint4* __restrict__ xs_in,   // xs2
                                 const uint4* __restrict__ xs1,
                                 const float4* __restrict__ x,
                                 float4* __restrict__ out, int N) {
    int t = blockIdx.x * blockDim.x + threadIdx.x;
    int v = t >> 5;
    if (v >= N) return;
    SPMM_ACCUM_BODY
    if (nb == 0) {
        float di = dinv[v];
        float rs = sqrtf((float)deg[v]);   // deg==0 -> 0, matches xs==0
        size_t idx = (size_t)v * 8 + sub;
        uint4 q1 = xs1[idx];
        uint4 q2 = xs_in[idx];
        float4 xa = x[(size_t)v * 16 + sub * 2];
        float4 xb = x[(size_t)v * 16 + sub * 2 + 1];
        float4 oa, ob;
        oa.x = 0.25f * (xa.x + rs * (blo(q1.x) + blo(q2.x)) + di * a0);
        oa.y = 0.25f * (xa.y + rs * (bhi(q1.x) + bhi(q2.x)) + di * a1);
        oa.z = 0.25f * (xa.z + rs * (blo(q1.y) + blo(q2.y)) + di * a2);
        oa.w = 0.25f * (xa.w + rs * (bhi(q1.y) + bhi(q2.y)) + di * a3);
        ob.x = 0.25f * (xb.x + rs * (blo(q1.z) + blo(q2.z)) + di * a4);
        ob.y = 0.25f * (xb.y + rs * (bhi(q1.z) + bhi(q2.z)) + di * a5);
        ob.z = 0.25f * (xb.z + rs * (blo(q1.w) + blo(q2.w)) + di * a6);
        ob.w = 0.25f * (xb.w + rs * (bhi(q1.w) + bhi(q2.w)) + di * a7);
        out[(size_t)v * 16 + sub * 2]     = oa;
        out[(size_t)v * 16 + sub * 2 + 1] = ob;
    }
}

extern "C" void kernel_launch(void* const* d_in, const int* in_sizes, int n_in,
                              void* d_out, int out_size, void* d_ws, size_t ws_size,
                              hipStream_t stream) {
    const float* x = (const float*)d_in[0];
    const int* adj = (const int*)d_in[1];
    float* out     = (float*)d_out;

    const int total_adj = in_sizes[1];   // 2*E entries in adj
    const int E = total_adj / 2;
    const int N = in_sizes[0] / DIM;
    const int NB = (N + BKT_G - 1) / BKT_G;   // dst buckets
    const int nhist = NB * NBLK;

    size_t BUF = (size_t)total_adj * 4;
    size_t xsb = (size_t)N * 32 * 4;
    if (xsb > BUF) BUF = xsb;
    BUF = (BUF + 255) & ~(size_t)255;

    char* ws = (char*)d_ws;
    int*      deg     = (int*)(ws);                               // 400KB
    float*    dinv    = (float*)(ws + (size_t)512 * 1024);        // 400KB
    int*      row_ptr = (int*)(ws + (size_t)1024 * 1024);         // 400KB+4
    int*      bsums   = (int*)(ws + (size_t)1536 * 1024);         // 1024 ints
    int*      hist    = (int*)(ws + (size_t)1600 * 1024);         // ~801KB
    int*      hist_s  = (int*)(ws + (size_t)2432 * 1024);         // ~801KB
    char*     big     = ws + (size_t)3264 * 1024;
    int*      csr_src = (int*)(big);
    unsigned* pairs   = (unsigned*)(big + BUF);     // dead after pass2
    uint4*    xs0     = (uint4*)(big + 2 * BUF);
    uint4*    xs1     = (uint4*)(big + 3 * BUF);
    uint4*    xs2     = (uint4*)(big + 4 * BUF);

    const int B = 256;

    // 1) per-(block,bucket) histogram — 4 LDS replicas, int4 loads
    hist_kernel<<<NBLK, HIST_B, NREP * NB * sizeof(int), stream>>>(adj, E, hist, NB);

    // 2) two-stage scan (bucket base == bsums[g])
    const int nscan2 = (nhist + SCAN_B - 1) / SCAN_B;
    scan_block_kernel<<<nscan2, SCAN_B, 0, stream>>>(hist, nhist, hist_s, bsums);
    scan_sums_kernel<<<1, 1024, 0, stream>>>(bsums, nscan2);

    // 3) placement into bucket-grouped pairs (int4 loads, fused scan fix-up)
    place_kernel<<<NBLK, HIST_B, NB * sizeof(int), stream>>>(adj, E, hist_s,
                                                             bsums, pairs, NB);

    // 4) per-bucket: deg/dinv/row_ptr + csr scatter + fused xs0 init
    pass2_build_kernel<<<NB, B, 0, stream>>>(pairs, bsums, (const float4*)x,
                                             csr_src, row_ptr, deg, dinv,
                                             xs0, N, NB, total_adj);

    // 5) layers 1,2 then fused layer3+final (2-deep gather pipeline)
    const int nblocks32 = (int)(((long long)N * 32 + B - 1) / B);
    spmm_bf16_kernel<<<nblocks32, B, 0, stream>>>(row_ptr, csr_src, dinv, xs0, xs1, N);
    spmm_bf16_kernel<<<nblocks32, B, 0, stream>>>(row_ptr, csr_src, dinv, xs1, xs2, N);
    spmm_last_kernel<<<nblocks32, B, 0, stream>>>(row_ptr, csr_src, dinv, deg,
                                                  xs2, xs1, (const float4*)x,
                                                  (float4*)out, N);
}